// Round 7
// baseline (105.598 us; speedup 1.0000x reference)
//
#include <hip/hip_runtime.h>
#include <math.h>

#define T_WAV   8388608
#define FRAME_L 1024
#define HOP     256
#define NF      32765            // (T_WAV - FRAME_L)/HOP + 1
#define HOPS    16               // hops (outputs/256) per block
#define OUT_PB  (HOPS * 256)     // 4096 outputs per block
#define NBLK    (T_WAV / OUT_PB) // 2048 blocks
#define NTHR    256

// Block L covers outputs [4096L, 4096L+4096) = hops 16L..16L+15, needing
// frames [16L-3, 16L+15] -> window of 5632 floats (22.5 KB) in LDS:
// amplification 1.375x (vs 1.75x in R5/R6), half the staging/barrier
// overhead per output. Frame params kept as a 4-wide sliding register
// window (8 VGPRs) so the 16x4 unroll stays under the 85-VGPR cap.
//
// Mask layout (proven R2-R6): pristine-restore may leave voiced_mask as
// int32 0/1 per frame or packed bool bytes. A byte at (bytelay ? f : 4*f)
// is correct for both (little-endian low byte).

__device__ __forceinline__ float psola_contrib(
    int e, float s, const float* __restrict__ fr,
    int j, float jfm, float wt)
{
    if (e < 0) return wt;                         // unvoiced frame
    if (j >= e) return 0.0f;                      // beyond resampled length
    float x  = fminf(fmaxf(fmaf(jfm, s, -0.5f), 0.0f), 1023.0f);
    int   x0 = (int)x;                            // x>=0 -> trunc == floor
    float w2 = x - (float)x0;
    float v0 = fr[x0];
    float v1 = fr[x0 + 1];                        // pad-safe; w2==0 at edge
    return fmaf(w2, v1 - v0, v0);
}

__global__ __launch_bounds__(256, 6) void psola_fused16(
    const float* __restrict__ wav,
    const float* __restrict__ src_f0,
    const float* __restrict__ tgt_f0,
    const unsigned int* __restrict__ mask_words,
    float*       __restrict__ out)
{
    __shared__ float s_wav[5636];    // 5632 window + pad for x0==1023 pair-read
    __shared__ float s_scl[19];
    __shared__ int   s_enc[19];

    const int p   = blockIdx.x;
    const int L   = ((p & 7) << 8) + (p >> 3);   // XCD swizzle (2048 = 8*256)
    const int tid = threadIdx.x;

    const int b0   = L << 4;                     // first hop index
    const int B    = L << 12;                    // first output sample
    const int f0   = (b0 > 3) ? (b0 - 3) : 0;
    const int f1   = ((b0 + 15) < NF - 1) ? (b0 + 15) : (NF - 1);
    const int base = f0 << 8;
    const int wlen = ((f1 - f0) << 8) + 1024;    // <= 5632, mult of 256

    // ---- stage wav window (coalesced float4; base 1 KiB aligned, end <= T_WAV)
    {
        const float4* g4 = (const float4*)(wav + base);
        float4*       s4 = (float4*)s_wav;
        const int nv = wlen >> 2;                // <= 1408
        for (int i = tid; i < nv; i += NTHR) s4[i] = g4[i];
    }
    if (tid == 0) s_wav[wlen] = 0.0f;

    // ---- per-frame params, threads 0..18
    if (tid < 19) {
        bool bytelay = false;
        #pragma unroll
        for (int i = 0; i < 16; ++i) {
            unsigned w = mask_words[i];
            if ((w & 0xFFFFFF00u) != 0u && w != 0xFFFFFFFFu) bytelay = true;
        }
        const int f = f0 + tid;
        if (f <= f1) {
            float src = src_f0[f];
            float tgt = tgt_f0[f];
            const unsigned char* m8 = (const unsigned char*)mask_words;
            unsigned off = bytelay ? (unsigned)f : ((unsigned)f << 2);
            bool valid = (m8[off] != 0) && (src >= 1.0f) && (tgt >= 1.0f);
            float denom = (tgt >= 1.0f) ? tgt : 1.0f;
            float ratio = fminf(fmaxf(src / denom, 0.25f), 4.0f);
            int nl = (int)rintf(1024.0f * ratio);   // round-half-even == jnp.round
            if (nl < 1) nl = 1;
            s_scl[tid] = 1024.0f / (float)nl;
            s_enc[tid] = valid ? nl : -1;
        } else {
            s_scl[tid] = 1.0f;
            s_enc[tid] = -1;
        }
    }

    // ---- hann values this thread ever needs: j = tid + 256*m, m=0..3
    float hh[4], jf[4];
    #pragma unroll
    for (int m = 0; m < 4; ++m) {
        int j = tid + (m << 8);
        hh[m] = 0.5f - 0.5f * cospif((float)j * (1.0f / 512.0f));
        jf[m] = (float)j + 0.5f;
    }
    float wsum4 = hh[0] + hh[1] + hh[2] + hh[3]; // == 2.0 up to fp rounding
    float rw4   = (wsum4 > 1e-8f) ? (1.0f / wsum4) : 1.0f;

    __syncthreads();

    if (f0 == b0 - 3 && (b0 + 15) <= NF - 1) {
        // interior: sliding 4-frame param window in registers.
        // hop k uses frames k..k+3: frame k+q pairs with m = 3-q.
        int   eA = s_enc[0], eB = s_enc[1], eC = s_enc[2], eD = s_enc[3];
        float cA = s_scl[0], cB = s_scl[1], cC = s_scl[2], cD = s_scl[3];

        #pragma unroll
        for (int k = 0; k < HOPS; ++k) {
            const float wt = s_wav[(k << 8) + tid + 768];  // unvoiced sample
            float acc;
            acc =      psola_contrib(eA, cA, s_wav + (k << 8),       tid + 768, jf[3], wt) * hh[3];
            acc = fmaf(psola_contrib(eB, cB, s_wav + ((k + 1) << 8), tid + 512, jf[2], wt), hh[2], acc);
            acc = fmaf(psola_contrib(eC, cC, s_wav + ((k + 2) << 8), tid + 256, jf[1], wt), hh[1], acc);
            acc = fmaf(psola_contrib(eD, cD, s_wav + ((k + 3) << 8), tid,       jf[0], wt), hh[0], acc);
            __builtin_nontemporal_store(acc * rw4, &out[B + (k << 8) + tid]);
            eA = eB; cA = cB;
            eB = eC; cB = cC;
            eC = eD; cC = cD;
            if (k < HOPS - 1) { eD = s_enc[k + 4]; cD = s_scl[k + 4]; }
        }
    } else {
        // edge blocks (L==0, L==NBLK-1 only): generic clamped frame loop
        for (int k = 0; k < HOPS; ++k) {
            const int t  = B + (k << 8) + tid;
            const int bt = t >> 8;
            int lo = bt - 3; if (lo < 0) lo = 0;
            int hi = bt;     if (hi > NF - 1) hi = NF - 1;
            float acc = 0.0f, wsum = 0.0f;
            for (int f = lo; f <= hi; ++f) {
                const int fi = f - f0;
                const int j  = t - (f << 8);
                const int m  = j >> 8;
                const float h = hh[m];
                const int   e = s_enc[fi];
                float val;
                if (e < 0) {
                    val = s_wav[t - base];
                } else if (j < e) {
                    float s  = s_scl[fi];
                    float x  = fminf(fmaxf(fmaf((float)j + 0.5f, s, -0.5f), 0.0f), 1023.0f);
                    int   x0 = (int)x;
                    float w2 = x - (float)x0;
                    const float* pp = &s_wav[(fi << 8) + x0];
                    val = fmaf(w2, pp[1] - pp[0], pp[0]);
                } else {
                    val = 0.0f;
                }
                acc  = fmaf(val, h, acc);
                wsum += h;
            }
            float o = (wsum > 1e-8f) ? (acc / wsum) : acc;
            __builtin_nontemporal_store(o, &out[t]);
        }
    }
}

extern "C" void kernel_launch(void* const* d_in, const int* in_sizes, int n_in,
                              void* d_out, int out_size, void* d_ws, size_t ws_size,
                              hipStream_t stream) {
    const float*        wav  = (const float*)d_in[0];
    const float*        src  = (const float*)d_in[1];
    const float*        tgt  = (const float*)d_in[2];
    const unsigned int* mask = (const unsigned int*)d_in[3];
    float*              out  = (float*)d_out;

    psola_fused16<<<NBLK, NTHR, 0, stream>>>(wav, src, tgt, mask, out);
}

// Round 8
// 97.266 us; speedup vs baseline: 1.0857x; 1.0857x over previous
//
#include <hip/hip_runtime.h>
#include <math.h>

#define T_WAV   8388608
#define FRAME_L 1024
#define HOP     256
#define NF      32765            // (T_WAV - FRAME_L)/HOP + 1
#define OUT_PB  2048             // outputs per block = 8 hops (R6 best)
#define NBLK    (T_WAV / OUT_PB) // 4096 blocks
#define NTHR    256

// R8 = R6 (best: 98.4 us) + two overlap levers:
//  (1) global_load_lds 16B staging — direct HBM->LDS DMA, no VGPR round-trip;
//      issued first so the DMA drains while params/hann compute proceeds.
//  (2) __launch_bounds__(256,8) — R6's (256,6) capped the CU at 24 waves while
//      LDS (14.3 KB) allows 11 blocks; wave cap was binding. 32 waves/CU.
//
// Mask layout (proven R2-R7): pristine-restore may leave voiced_mask as int32
// 0/1 per frame or packed bool bytes. A byte at (bytelay ? f : 4*f) is correct
// for both (little-endian low byte). int32 0/1 words never have bits in bytes
// 1..3; packed-bool words do with p=0.992/word -> 16-word scan never misses.

typedef const __attribute__((address_space(1))) unsigned char g_u8;
typedef __attribute__((address_space(3))) unsigned char l_u8;

__global__ __launch_bounds__(256, 8) void psola_fused(
    const float* __restrict__ wav,
    const float* __restrict__ src_f0,
    const float* __restrict__ tgt_f0,
    const unsigned int* __restrict__ mask_words,
    float*       __restrict__ out)
{
    __shared__ float s_wav[3588];    // 3584 window + pad for x0==1023 pair-read
    __shared__ float s_scl[11];
    __shared__ int   s_enc[11];

    const int p   = blockIdx.x;
    const int L   = ((p & 7) << 9) + (p >> 3);   // XCD swizzle (4096 = 8*512)
    const int tid = threadIdx.x;
    const int lane = tid & 63;
    const int wv   = tid >> 6;                   // wave id 0..3

    const int b0   = L << 3;                     // first hop index
    const int B    = L << 11;                    // first output sample
    const int f0   = (b0 > 3) ? (b0 - 3) : 0;
    const int f1   = ((b0 + 7) < NF - 1) ? (b0 + 7) : (NF - 1);
    const int base = f0 << 8;
    const int wlen = ((f1 - f0) << 8) + 1024;    // <= 3584, multiple of 256

    // ---- stage wav window: direct HBM->LDS DMA, 1 KB per wave-issue.
    // Each wave's 64 lanes load 16 B from g + lane*16 into LDS base + lane*16
    // (wave-uniform base + lane*size — exactly our contiguous layout).
    {
        const int nseg = wlen >> 8;              // 256-float (1 KB) segments, <= 14
        for (int seg = wv; seg < nseg; seg += 4) {
            const float* gp = wav + base + (seg << 8) + (lane << 2);
            float*       lp = s_wav + (seg << 8) + (lane << 2);
            __builtin_amdgcn_global_load_lds((g_u8*)gp, (l_u8*)lp, 16, 0, 0);
        }
    }
    if (tid == 0) s_wav[wlen] = 0.0f;

    // ---- per-frame params, threads 0..10 (overlaps the staging DMA drain)
    if (tid < 11) {
        bool bytelay = false;
        #pragma unroll
        for (int i = 0; i < 16; ++i) {
            unsigned w = mask_words[i];
            if ((w & 0xFFFFFF00u) != 0u && w != 0xFFFFFFFFu) bytelay = true;
        }
        const int f = f0 + tid;
        if (f <= f1) {
            float src = src_f0[f];
            float tgt = tgt_f0[f];
            const unsigned char* m8 = (const unsigned char*)mask_words;
            unsigned off = bytelay ? (unsigned)f : ((unsigned)f << 2);
            bool valid = (m8[off] != 0) && (src >= 1.0f) && (tgt >= 1.0f);
            float denom = (tgt >= 1.0f) ? tgt : 1.0f;
            float ratio = fminf(fmaxf(src / denom, 0.25f), 4.0f);
            int nl = (int)rintf(1024.0f * ratio);   // round-half-even == jnp.round
            if (nl < 1) nl = 1;
            s_scl[tid] = 1024.0f / (float)nl;
            s_enc[tid] = valid ? nl : -1;
        } else {
            s_scl[tid] = 1.0f;
            s_enc[tid] = -1;
        }
    }

    // ---- hann values this thread ever needs: j = tid + 256*m, m=0..3
    float hh[4], jf[4];
    #pragma unroll
    for (int m = 0; m < 4; ++m) {
        int j = tid + (m << 8);
        hh[m] = 0.5f - 0.5f * cospif((float)j * (1.0f / 512.0f));
        jf[m] = (float)j + 0.5f;
    }
    float wsum4 = hh[0] + hh[1] + hh[2] + hh[3]; // == 2.0 up to fp rounding
    float rw4   = (wsum4 > 1e-8f) ? (1.0f / wsum4) : 1.0f;

    __syncthreads();   // drains vmcnt (DMA) + lgkmcnt

    if (f0 == b0 - 3 && (b0 + 7) <= NF - 1) {
        // interior: params in registers (literal indices after full unroll)
        int   enc_r[11];
        float scl_r[11];
        #pragma unroll
        for (int i = 0; i < 11; ++i) { enc_r[i] = s_enc[i]; scl_r[i] = s_scl[i]; }

        #pragma unroll
        for (int k = 0; k < 8; ++k) {                 // hop k (literal)
            const float wt  = s_wav[(k << 8) + tid + 768];  // unvoiced sample
            float acc = 0.0f;
            #pragma unroll
            for (int q = 0; q < 4; ++q) {
                const int fi = k + q;                 // LITERAL frame index
                const int m  = 3 - q;                 // j = tid + m*256
                const int e  = enc_r[fi];
                const int j  = tid + (m << 8);
                float val;
                if (e < 0) {
                    val = wt;
                } else if (j < e) {
                    float s  = scl_r[fi];
                    float x  = fminf(fmaxf(fmaf(jf[m], s, -0.5f), 0.0f), 1023.0f);
                    int   x0 = (int)x;
                    float w2 = x - (float)x0;
                    const float* pp = &s_wav[(fi << 8) + x0];
                    float v0 = pp[0];
                    float v1 = pp[1];                 // pad-safe; w2==0 at edge
                    val = fmaf(w2, v1 - v0, v0);
                } else {
                    val = 0.0f;
                }
                acc = fmaf(val, hh[m], acc);
            }
            __builtin_nontemporal_store(acc * rw4, &out[B + (k << 8) + tid]);
        }
    } else {
        // edge blocks (L==0, L==NBLK-1 only): generic clamped frame loop
        for (int k = 0; k < 8; ++k) {
            const int t  = B + (k << 8) + tid;
            const int bt = t >> 8;
            int lo = bt - 3; if (lo < 0) lo = 0;
            int hi = bt;     if (hi > NF - 1) hi = NF - 1;
            float acc = 0.0f, wsum = 0.0f;
            for (int f = lo; f <= hi; ++f) {
                const int fi = f - f0;
                const int j  = t - (f << 8);
                const int m  = j >> 8;
                const float h = hh[m];
                const int   e = s_enc[fi];
                float val;
                if (e < 0) {
                    val = s_wav[t - base];
                } else if (j < e) {
                    float s  = s_scl[fi];
                    float x  = fminf(fmaxf(fmaf((float)j + 0.5f, s, -0.5f), 0.0f), 1023.0f);
                    int   x0 = (int)x;
                    float w2 = x - (float)x0;
                    const float* pp = &s_wav[(fi << 8) + x0];
                    val = fmaf(w2, pp[1] - pp[0], pp[0]);
                } else {
                    val = 0.0f;
                }
                acc  = fmaf(val, h, acc);
                wsum += h;
            }
            float o = (wsum > 1e-8f) ? (acc / wsum) : acc;
            __builtin_nontemporal_store(o, &out[t]);
        }
    }
}

extern "C" void kernel_launch(void* const* d_in, const int* in_sizes, int n_in,
                              void* d_out, int out_size, void* d_ws, size_t ws_size,
                              hipStream_t stream) {
    const float*        wav  = (const float*)d_in[0];
    const float*        src  = (const float*)d_in[1];
    const float*        tgt  = (const float*)d_in[2];
    const unsigned int* mask = (const unsigned int*)d_in[3];
    float*              out  = (float*)d_out;

    psola_fused<<<NBLK, NTHR, 0, stream>>>(wav, src, tgt, mask, out);
}